// Round 4
// baseline (131.372 us; speedup 1.0000x reference)
//
#include <hip/hip_runtime.h>
#include <math.h>

#define N_NODES 1024
#define F_DIM   128
#define M_DIM   256
#define E_DIM   8
#define P_PAIRS 523776   // N*(N-1)/2
#define NBLK    1056     // sum_{tj=0..31} (2*tj+2) 16x32 tiles
#define APITCH  33       // padded row pitch in float4 (bank-decorrelating)
#define WPITCH  36       // kA W1-tile row pitch in dwords (32 k + 4 pad, 16B-aligned)

typedef float v2f __attribute__((ext_vector_type(2)));

// ---------- Kernel A (R20): old full-GPU shape + coalesced W1 LDS staging ----------
// R19 post-mortem: (a) runtime-selected acc pointer ((c<4)?accA:accB) forced the
// accumulators to scratch (rule #20 violation) and (b) the 129-block grid used
// half the GPU. R20 keeps the PROVEN 257-block / 4-node shape and changes ONLY
// the W1 access path: old per-thread-row global reads touched 64 distinct cache
// lines per wave-instr (stride 1040B, 25% line utilization); now W1 is staged in
// eight [256m x 32k] LDS chunks with coalesced float4 loads (8x128B segments per
// wave-instr, 100% utilization), register-prefetched one chunk ahead so the L2
// latency hides under the previous chunk's 128 FMAs. Thread t reads its own row
// back as 8 ds_read_b128 (pitch 36 dwords: 2 lanes/bank-quad per 16-lane phase =
// conflict-free). Accumulator binding is STATIC (lambda taking float(&)[4],
// called once per half) -> no scratch. FMA chain per output is k-ascending,
// x,y,z,w within each float4 -- identical order to the old kernel -> bit-exact.
__global__ __launch_bounds__(256) void kA(const float* __restrict__ x,
                                          const float* __restrict__ ctx,
                                          const float* __restrict__ W1,
                                          const float* __restrict__ b1,
                                          const float* __restrict__ gamma,
                                          const float* __restrict__ beta,
                                          const float* __restrict__ rmean,
                                          const float* __restrict__ rvar,
                                          const float* __restrict__ W2,
                                          const float* __restrict__ b2,
                                          float* __restrict__ pa,
                                          float* __restrict__ pb,
                                          float* __restrict__ stress,
                                          float* __restrict__ w2ft,
                                          float* __restrict__ b2f) {
  const int t = threadIdx.x;

  if (blockIdx.x == 256) {   // BN fold + b2 fold block (unchanged)
    __shared__ float bnbs[256];
    const float s   = gamma[t] / sqrtf(rvar[t] + 1e-5f);
    bnbs[t] = beta[t] - s * rmean[t];
    #pragma unroll
    for (int e = 0; e < 8; ++e) w2ft[t * 8 + e] = W2[e * 256 + t] * s;
    __syncthreads();
    const int wv = t >> 6, lane = t & 63;
    #pragma unroll
    for (int r = 0; r < 2; ++r) {
      const int e = wv * 2 + r;
      float acc = 0.f;
      #pragma unroll
      for (int k = 0; k < 4; ++k) acc += W2[e * 256 + lane + 64 * k] * bnbs[lane + 64 * k];
      #pragma unroll
      for (int m = 32; m > 0; m >>= 1) acc += __shfl_xor(acc, m, 64);
      if (lane == 0) b2f[e] = acc + b2[e];
    }
    return;
  }

  __shared__ float wt[256 * WPITCH];   // 36 KB: one 256x32 W1 k-chunk
  __shared__ float xv[4][128];         // 2 KB
  const int n0 = blockIdx.x * 4;

  const float4* W14 = (const float4*)W1;   // row stride 65 float4 (260 floats)
  const int wr = t >> 3, wc = t & 7;       // staging: row group + float4 col

  // stage xv (coalesced) + W1 chunk 0
  if (t < 128) {
    ((float4*)&xv[0][0])[t] = ((const float4*)(x + (size_t)n0 * F_DIM))[t];
  }
  #pragma unroll
  for (int q = 0; q < 8; ++q) {
    const int rr = q * 32 + wr;
    *(float4*)&wt[rr * WPITCH + wc * 4] = W14[(size_t)rr * 65 + wc];
  }
  __syncthreads();

  // stress for the 4 nodes (1 per wave -- unchanged math)
  {
    const int wv = t >> 6, lane = t & 63;
    const float a = xv[wv][lane], b = xv[wv][lane + 64];
    float sum = a + b;
    #pragma unroll
    for (int m = 32; m > 0; m >>= 1) sum += __shfl_xor(sum, m, 64);
    const float mean = sum * (1.0f / 128.0f);
    const float d0 = a - mean, d1 = b - mean;
    float ss = d0 * d0 + d1 * d1;
    #pragma unroll
    for (int m = 32; m > 0; m >>= 1) ss += __shfl_xor(ss, m, 64);
    if (lane == 0) stress[n0 + wv] = sqrtf(ss * (1.0f / 127.0f));
  }

  float accA[4] = {0.f, 0.f, 0.f, 0.f};
  float accB[4] = {0.f, 0.f, 0.f, 0.f};

  // one chunk: prefetch next to regs, compute current, write next to LDS.
  // acc is statically bound per call site (no runtime pointer -> no scratch).
  auto doChunk = [&](int c, float (&acc)[4]) {
    float4 pre[8];
    if (c < 7) {
      #pragma unroll
      for (int q = 0; q < 8; ++q) {
        const int rr = q * 32 + wr;
        pre[q] = W14[(size_t)rr * 65 + (c + 1) * 8 + wc];
      }
    }
    float4 wreg[8];
    #pragma unroll
    for (int k4 = 0; k4 < 8; ++k4) wreg[k4] = *(const float4*)&wt[t * WPITCH + k4 * 4];
    const int xb = (c & 3) * 8;   // float4 index base into xv row
    #pragma unroll
    for (int k4 = 0; k4 < 8; ++k4) {
      const float4 w4 = wreg[k4];
      #pragma unroll
      for (int nn = 0; nn < 4; ++nn) {
        const float4 xf = ((const float4*)&xv[nn][0])[xb + k4];   // LDS broadcast
        acc[nn] = fmaf(xf.w, w4.w, fmaf(xf.z, w4.z, fmaf(xf.y, w4.y, fmaf(xf.x, w4.x, acc[nn]))));
      }
    }
    if (c < 7) {
      __syncthreads();   // everyone done reading wt
      #pragma unroll
      for (int q = 0; q < 8; ++q) {
        const int rr = q * 32 + wr;
        *(float4*)&wt[rr * WPITCH + wc * 4] = pre[q];
      }
      __syncthreads();   // chunk c+1 visible
    }
  };

  // chunks 0..3: A-weights (cols 0..127); 4..7: B-weights (cols 128..255)
  doChunk(0, accA); doChunk(1, accA); doChunk(2, accA); doChunk(3, accA);
  doChunk(4, accB); doChunk(5, accB); doChunk(6, accB); doChunk(7, accB);

  // ctx fold + writes (identical expressions -> bit-exact)
  const float c0 = ctx[0], c1 = ctx[1], c2 = ctx[2], c3 = ctx[3];
  const float* rowt = W1 + (size_t)t * 260 + 256;
  const float ctv = b1[t] + c0 * rowt[0] + c1 * rowt[1] + c2 * rowt[2] + c3 * rowt[3];
  #pragma unroll
  for (int nn = 0; nn < 4; ++nn) {
    pa[(size_t)(n0 + nn) * M_DIM + t] = accA[nn] + ctv;
    pb[(size_t)(n0 + nn) * M_DIM + t] = accB[nn];
  }
}

// ---------- Kernel C: 1056 triangular 16x32 tiles, 256 threads, 2 pairs/thread ----------
// R16 form, untouched (41.7-41.9 us measured; R17 pipeline was a compiler no-op,
// R18 4-pairs/thread regressed: wall tracks wave residency and 2 pairs/thread at
// 256thr x 1056 blocks is the occupancy-optimal point).
__global__ __launch_bounds__(256, 6) void kC(const float* __restrict__ pa,
                                             const float* __restrict__ pb,
                                             const float* __restrict__ w2ft,
                                             const float* __restrict__ b2f,
                                             const float* __restrict__ W3,
                                             const float* __restrict__ b3,
                                             const float* __restrict__ stress,
                                             float* __restrict__ out) {
  __shared__ float4 a4[16 * APITCH];   // 16 i-rows, 128-m chunk, pitch 33
  __shared__ float4 b4[32 * APITCH];   // 32 j-rows
  const int t = threadIdx.x;

  // decode p -> (tj, si): p = tj*(tj+1) + si, si in [0, 2*tj+2)
  const int p = blockIdx.x;
  int tj = (int)((sqrtf(4.0f * (float)p + 1.0f) - 1.0f) * 0.5f);
  while ((tj + 1) * (tj + 2) <= p) ++tj;
  while (tj * (tj + 1) > p) --tj;
  const int si = p - tj * (tj + 1);
  const int i0 = si * 16, j0 = tj * 32;

  const float4* pa4 = (const float4*)pa;
  const float4* pb4 = (const float4*)pb;
  const double* wdp = (const double*)w2ft;   // row m: 4 doubles = e-pairs

  // ---- chunk-0 staging loads issued; stress-mean computed under their latency ----
  float4 rA[2], rB[4];
  #pragma unroll
  for (int q = 0; q < 2; ++q) {
    const int d = q * 256 + t, r = d >> 5, c = d & 31;
    rA[q] = pa4[(size_t)(i0 + r) * 64 + c];
  }
  #pragma unroll
  for (int q = 0; q < 4; ++q) {
    const int d = q * 256 + t, r = d >> 5, c = d & 31;
    rB[q] = pb4[(size_t)(j0 + r) * 64 + c];
  }

  float ssum = 0.f;
  {
    const int lane = t & 63;
    #pragma unroll
    for (int k = 0; k < 16; ++k) ssum += stress[lane + 64 * k];
    #pragma unroll
    for (int m = 32; m > 0; m >>= 1) ssum += __shfl_xor(ssum, m, 64);
  }
  const float smean = ssum * (1.0f / 1024.0f);

  // ---- write chunk-0 tiles (transient regs die here; no spill risk) ----
  #pragma unroll
  for (int q = 0; q < 2; ++q) {
    const int d = q * 256 + t, r = d >> 5, c = d & 31;
    a4[r * APITCH + c] = rA[q];
  }
  #pragma unroll
  for (int q = 0; q < 4; ++q) {
    const int d = q * 256 + t, r = d >> 5, c = d & 31;
    b4[r * APITCH + c] = rB[q];
  }
  __syncthreads();

  const int jx = t & 15;   // j pair: jx, jx+16
  const int iy = t >> 4;   // i within tile, 0..15
  v2f acc[8];              // per e: {acc for j=jx, acc for j=jx+16}
  #pragma unroll
  for (int e = 0; e < 8; ++e) acc[e] = (v2f){0.f, 0.f};

  const float4* aRow  = a4 + iy * APITCH;          // bases hoisted; m4 offsets immediate
  const float4* bRow0 = b4 + jx * APITCH;
  const float4* bRow1 = b4 + (jx + 16) * APITCH;

  auto computeChunk = [&](int cw) {
    #pragma unroll 2
    for (int m4 = 0; m4 < 32; ++m4) {
      const float4 A  = aRow[m4];
      const float4 B0 = bRow0[m4];
      const float4 B1 = bRow1[m4];
      const double* wr = wdp + (size_t)(cw + m4) * 16;   // 4 m x 4 e-pair doubles
      const float* Af  = (const float*)&A;
      const float* B0f = (const float*)&B0;
      const float* B1f = (const float*)&B1;
      #pragma unroll
      for (int mm = 0; mm < 4; ++mm) {
        v2f R;
        R.x = fmaxf(Af[mm] + B0f[mm], 0.f);   // r for (i, jx)
        R.y = fmaxf(Af[mm] + B1f[mm], 0.f);   // r for (i, jx+16)
        #pragma unroll
        for (int k = 0; k < 4; ++k) {
          const double wp = wr[mm * 4 + k];   // {w[m][2k], w[m][2k+1]} in SGPR pair
          // even e = 2k: broadcast LO word of wp to both halves (R9-proven form)
          asm("v_pk_fma_f32 %0, %1, %2, %0 op_sel:[0,0,0] op_sel_hi:[0,1,1]"
              : "+v"(acc[2 * k]) : "s"(wp), "v"(R));
          // odd e = 2k+1: broadcast HI word of wp to both halves
          asm("v_pk_fma_f32 %0, %1, %2, %0 op_sel:[1,0,0] op_sel_hi:[1,1,1]"
              : "+v"(acc[2 * k + 1]) : "s"(wp), "v"(R));
        }
      }
    }
  };

  computeChunk(0);
  __syncthreads();

  // ---- stage chunk 1 (transient regs again) ----
  #pragma unroll
  for (int q = 0; q < 2; ++q) {
    const int d = q * 256 + t, r = d >> 5, c = d & 31;
    rA[q] = pa4[(size_t)(i0 + r) * 64 + 32 + c];
  }
  #pragma unroll
  for (int q = 0; q < 4; ++q) {
    const int d = q * 256 + t, r = d >> 5, c = d & 31;
    rB[q] = pb4[(size_t)(j0 + r) * 64 + 32 + c];
  }
  #pragma unroll
  for (int q = 0; q < 2; ++q) {
    const int d = q * 256 + t, r = d >> 5, c = d & 31;
    a4[r * APITCH + c] = rA[q];
  }
  #pragma unroll
  for (int q = 0; q < 4; ++q) {
    const int d = q * 256 + t, r = d >> 5, c = d & 31;
    b4[r * APITCH + c] = rB[q];
  }
  __syncthreads();

  computeChunk(32);

  // ---- epilogue ----
  float w3v[8], b2v[8];
  #pragma unroll
  for (int e = 0; e < 8; ++e) { w3v[e] = W3[e]; b2v[e] = b2f[e]; }
  const float b3v = b3[0];
  const int i = i0 + iy;
  #pragma unroll
  for (int jb = 0; jb < 2; ++jb) {
    const int j = j0 + jx + jb * 16;
    if (i < j) {
      float logit = b3v;
      #pragma unroll
      for (int e = 0; e < 8; ++e) {
        const float av = jb ? acc[e].y : acc[e].x;
        const float h2 = fmaxf(av + b2v[e], 0.f);
        logit = fmaf(w3v[e], h2, logit);
      }
      const float score = 1.0f / (1.0f + expf(-logit));
      const int idx = i * 1023 - (i * (i - 1)) / 2 + (j - i - 1);
      out[idx] = score;
      const bool mk = (score > 0.5f) && (stress[i] > smean) && (stress[j] > smean);
      out[P_PAIRS + idx] = mk ? 1.0f : 0.0f;
    }
  }
}

extern "C" void kernel_launch(void* const* d_in, const int* in_sizes, int n_in,
                              void* d_out, int out_size, void* d_ws, size_t ws_size,
                              hipStream_t stream) {
  const float* x     = (const float*)d_in[0];
  const float* ctx   = (const float*)d_in[1];
  const float* W1    = (const float*)d_in[2];
  const float* b1    = (const float*)d_in[3];
  const float* gamma = (const float*)d_in[4];
  const float* beta  = (const float*)d_in[5];
  const float* rmean = (const float*)d_in[6];
  const float* rvar  = (const float*)d_in[7];
  const float* W2    = (const float*)d_in[8];
  const float* b2    = (const float*)d_in[9];
  const float* W3    = (const float*)d_in[10];
  const float* b3    = (const float*)d_in[11];
  float* out = (float*)d_out;

  float* ws     = (float*)d_ws;
  float* pa     = ws;              // 1024*256 (cterm pre-folded)
  float* pb     = pa + 262144;     // 1024*256
  float* w2ft   = pb + 262144;     // 256*8 (transposed [m][e], BN-scaled)
  float* b2f    = w2ft + 2048;     // 8
  float* stress = b2f + 8;         // 1024

  hipLaunchKernelGGL(kA, dim3(257), dim3(256), 0, stream, x, ctx, W1, b1, gamma, beta,
                     rmean, rvar, W2, b2, pa, pb, stress, w2ft, b2f);
  hipLaunchKernelGGL(kC, dim3(NBLK), dim3(256), 0, stream, pa, pb, w2ft, b2f,
                     W3, b3, stress, out);
}

// Round 5
// 121.527 us; speedup vs baseline: 1.0810x; 1.0810x over previous
//
#include <hip/hip_runtime.h>
#include <math.h>

#define N_NODES 1024
#define F_DIM   128
#define M_DIM   256
#define E_DIM   8
#define P_PAIRS 523776   // N*(N-1)/2
#define NBLK    1056     // sum_{tj=0..31} (2*tj+2) 16x32 tiles
#define APITCH  33       // padded row pitch in float4 (bank-decorrelating)

typedef float v2f __attribute__((ext_vector_type(2)));

// ---------- Kernel A: pa/pb projections (+cterm folded) + stress; block 256 = BN fold ----------
// R21: exact revert to the R0/best-measured form. R19/R20 "coalescing fixes"
// both regressed (~+10 us): the per-thread-row stream is NOT over-fetching
// (every byte of row t is consumed by thread t; L2-resident), its TA-request
// cost is ~2 us, and it needs zero barriers -- while the LDS-staged variants
// pay 16 syncthreads/block at 1 block/CU residency (exposed L2 latency, no
// TLP cover). kA is ~3-5 us; leave it alone.
__global__ __launch_bounds__(256) void kA(const float* __restrict__ x,
                                          const float* __restrict__ ctx,
                                          const float* __restrict__ W1,
                                          const float* __restrict__ b1,
                                          const float* __restrict__ gamma,
                                          const float* __restrict__ beta,
                                          const float* __restrict__ rmean,
                                          const float* __restrict__ rvar,
                                          const float* __restrict__ W2,
                                          const float* __restrict__ b2,
                                          float* __restrict__ pa,
                                          float* __restrict__ pb,
                                          float* __restrict__ stress,
                                          float* __restrict__ w2ft,
                                          float* __restrict__ b2f) {
  const int t = threadIdx.x;

  if (blockIdx.x == 256) {
    __shared__ float bnbs[256];
    const float s   = gamma[t] / sqrtf(rvar[t] + 1e-5f);
    bnbs[t] = beta[t] - s * rmean[t];
    #pragma unroll
    for (int e = 0; e < 8; ++e) w2ft[t * 8 + e] = W2[e * 256 + t] * s;
    __syncthreads();
    const int wv = t >> 6, lane = t & 63;
    #pragma unroll
    for (int r = 0; r < 2; ++r) {
      const int e = wv * 2 + r;
      float acc = 0.f;
      #pragma unroll
      for (int k = 0; k < 4; ++k) acc += W2[e * 256 + lane + 64 * k] * bnbs[lane + 64 * k];
      #pragma unroll
      for (int m = 32; m > 0; m >>= 1) acc += __shfl_xor(acc, m, 64);
      if (lane == 0) b2f[e] = acc + b2[e];
    }
    return;
  }

  __shared__ float xv[4][128];
  const int n0 = blockIdx.x * 4;
  if (t < 128) {
    ((float4*)&xv[0][0])[t] = ((const float4*)(x + (size_t)n0 * F_DIM))[t];
  }
  __syncthreads();

  {
    const int wv = t >> 6, lane = t & 63;
    const float a = xv[wv][lane], b = xv[wv][lane + 64];
    float sum = a + b;
    #pragma unroll
    for (int m = 32; m > 0; m >>= 1) sum += __shfl_xor(sum, m, 64);
    const float mean = sum * (1.0f / 128.0f);
    const float d0 = a - mean, d1 = b - mean;
    float ss = d0 * d0 + d1 * d1;
    #pragma unroll
    for (int m = 32; m > 0; m >>= 1) ss += __shfl_xor(ss, m, 64);
    if (lane == 0) stress[n0 + wv] = sqrtf(ss * (1.0f / 127.0f));
  }

  const float4* wrow = (const float4*)(W1 + (size_t)t * 260);  // W1 row-major [256][260]
  float accA[4] = {0.f, 0.f, 0.f, 0.f};
  float accB[4] = {0.f, 0.f, 0.f, 0.f};
  #pragma unroll 8
  for (int k4 = 0; k4 < 32; ++k4) {
    const float4 wa = wrow[k4];
    const float4 wb = wrow[32 + k4];
    #pragma unroll
    for (int nn = 0; nn < 4; ++nn) {
      const float4 xf = ((const float4*)&xv[nn][0])[k4];
      accA[nn] = fmaf(xf.w, wa.w, fmaf(xf.z, wa.z, fmaf(xf.y, wa.y, fmaf(xf.x, wa.x, accA[nn]))));
      accB[nn] = fmaf(xf.w, wb.w, fmaf(xf.z, wb.z, fmaf(xf.y, wb.y, fmaf(xf.x, wb.x, accB[nn]))));
    }
  }
  const float c0 = ctx[0], c1 = ctx[1], c2 = ctx[2], c3 = ctx[3];
  const float* rowt = W1 + (size_t)t * 260 + 256;
  const float ctv = b1[t] + c0 * rowt[0] + c1 * rowt[1] + c2 * rowt[2] + c3 * rowt[3];
  #pragma unroll
  for (int nn = 0; nn < 4; ++nn) {
    pa[(size_t)(n0 + nn) * M_DIM + t] = accA[nn] + ctv;   // cterm folded (bit-exact)
    pb[(size_t)(n0 + nn) * M_DIM + t] = accB[nn];
  }
}

// ---------- Kernel C: 1056 triangular 16x32 tiles, 256 threads, 2 pairs/thread ----------
// R16 form, untouched (41.7-41.9 us measured across 4 sessions). Structural
// plateau confirmed by three failed attacks: R17 sw-pipeline (null -- compiler
// already schedules), R18 4-pairs/thread (-4 us, residency loss), R19+ kA-side
// experiments (kC byte-identical, unchanged counters). Demand floors: VALU
// ~13 us, LDS ~16 us; the 42-us wall is barrier/latency slack that neither
// source pipelining nor occupancy hints recover.
__global__ __launch_bounds__(256, 6) void kC(const float* __restrict__ pa,
                                             const float* __restrict__ pb,
                                             const float* __restrict__ w2ft,
                                             const float* __restrict__ b2f,
                                             const float* __restrict__ W3,
                                             const float* __restrict__ b3,
                                             const float* __restrict__ stress,
                                             float* __restrict__ out) {
  __shared__ float4 a4[16 * APITCH];   // 16 i-rows, 128-m chunk, pitch 33
  __shared__ float4 b4[32 * APITCH];   // 32 j-rows
  const int t = threadIdx.x;

  // decode p -> (tj, si): p = tj*(tj+1) + si, si in [0, 2*tj+2)
  const int p = blockIdx.x;
  int tj = (int)((sqrtf(4.0f * (float)p + 1.0f) - 1.0f) * 0.5f);
  while ((tj + 1) * (tj + 2) <= p) ++tj;
  while (tj * (tj + 1) > p) --tj;
  const int si = p - tj * (tj + 1);
  const int i0 = si * 16, j0 = tj * 32;

  const float4* pa4 = (const float4*)pa;
  const float4* pb4 = (const float4*)pb;
  const double* wdp = (const double*)w2ft;   // row m: 4 doubles = e-pairs

  // ---- chunk-0 staging loads issued; stress-mean computed under their latency ----
  float4 rA[2], rB[4];
  #pragma unroll
  for (int q = 0; q < 2; ++q) {
    const int d = q * 256 + t, r = d >> 5, c = d & 31;
    rA[q] = pa4[(size_t)(i0 + r) * 64 + c];
  }
  #pragma unroll
  for (int q = 0; q < 4; ++q) {
    const int d = q * 256 + t, r = d >> 5, c = d & 31;
    rB[q] = pb4[(size_t)(j0 + r) * 64 + c];
  }

  float ssum = 0.f;
  {
    const int lane = t & 63;
    #pragma unroll
    for (int k = 0; k < 16; ++k) ssum += stress[lane + 64 * k];
    #pragma unroll
    for (int m = 32; m > 0; m >>= 1) ssum += __shfl_xor(ssum, m, 64);
  }
  const float smean = ssum * (1.0f / 1024.0f);

  // ---- write chunk-0 tiles (transient regs die here; no spill risk) ----
  #pragma unroll
  for (int q = 0; q < 2; ++q) {
    const int d = q * 256 + t, r = d >> 5, c = d & 31;
    a4[r * APITCH + c] = rA[q];
  }
  #pragma unroll
  for (int q = 0; q < 4; ++q) {
    const int d = q * 256 + t, r = d >> 5, c = d & 31;
    b4[r * APITCH + c] = rB[q];
  }
  __syncthreads();

  const int jx = t & 15;   // j pair: jx, jx+16
  const int iy = t >> 4;   // i within tile, 0..15
  v2f acc[8];              // per e: {acc for j=jx, acc for j=jx+16}
  #pragma unroll
  for (int e = 0; e < 8; ++e) acc[e] = (v2f){0.f, 0.f};

  const float4* aRow  = a4 + iy * APITCH;          // bases hoisted; m4 offsets immediate
  const float4* bRow0 = b4 + jx * APITCH;
  const float4* bRow1 = b4 + (jx + 16) * APITCH;

  auto computeChunk = [&](int cw) {
    #pragma unroll 2
    for (int m4 = 0; m4 < 32; ++m4) {
      const float4 A  = aRow[m4];
      const float4 B0 = bRow0[m4];
      const float4 B1 = bRow1[m4];
      const double* wr = wdp + (size_t)(cw + m4) * 16;   // 4 m x 4 e-pair doubles
      const float* Af  = (const float*)&A;
      const float* B0f = (const float*)&B0;
      const float* B1f = (const float*)&B1;
      #pragma unroll
      for (int mm = 0; mm < 4; ++mm) {
        v2f R;
        R.x = fmaxf(Af[mm] + B0f[mm], 0.f);   // r for (i, jx)
        R.y = fmaxf(Af[mm] + B1f[mm], 0.f);   // r for (i, jx+16)
        #pragma unroll
        for (int k = 0; k < 4; ++k) {
          const double wp = wr[mm * 4 + k];   // {w[m][2k], w[m][2k+1]} in SGPR pair
          // even e = 2k: broadcast LO word of wp to both halves (R9-proven form)
          asm("v_pk_fma_f32 %0, %1, %2, %0 op_sel:[0,0,0] op_sel_hi:[0,1,1]"
              : "+v"(acc[2 * k]) : "s"(wp), "v"(R));
          // odd e = 2k+1: broadcast HI word of wp to both halves
          asm("v_pk_fma_f32 %0, %1, %2, %0 op_sel:[1,0,0] op_sel_hi:[1,1,1]"
              : "+v"(acc[2 * k + 1]) : "s"(wp), "v"(R));
        }
      }
    }
  };

  computeChunk(0);
  __syncthreads();

  // ---- stage chunk 1 (transient regs again) ----
  #pragma unroll
  for (int q = 0; q < 2; ++q) {
    const int d = q * 256 + t, r = d >> 5, c = d & 31;
    rA[q] = pa4[(size_t)(i0 + r) * 64 + 32 + c];
  }
  #pragma unroll
  for (int q = 0; q < 4; ++q) {
    const int d = q * 256 + t, r = d >> 5, c = d & 31;
    rB[q] = pb4[(size_t)(j0 + r) * 64 + 32 + c];
  }
  #pragma unroll
  for (int q = 0; q < 2; ++q) {
    const int d = q * 256 + t, r = d >> 5, c = d & 31;
    a4[r * APITCH + c] = rA[q];
  }
  #pragma unroll
  for (int q = 0; q < 4; ++q) {
    const int d = q * 256 + t, r = d >> 5, c = d & 31;
    b4[r * APITCH + c] = rB[q];
  }
  __syncthreads();

  computeChunk(32);

  // ---- epilogue ----
  float w3v[8], b2v[8];
  #pragma unroll
  for (int e = 0; e < 8; ++e) { w3v[e] = W3[e]; b2v[e] = b2f[e]; }
  const float b3v = b3[0];
  const int i = i0 + iy;
  #pragma unroll
  for (int jb = 0; jb < 2; ++jb) {
    const int j = j0 + jx + jb * 16;
    if (i < j) {
      float logit = b3v;
      #pragma unroll
      for (int e = 0; e < 8; ++e) {
        const float av = jb ? acc[e].y : acc[e].x;
        const float h2 = fmaxf(av + b2v[e], 0.f);
        logit = fmaf(w3v[e], h2, logit);
      }
      const float score = 1.0f / (1.0f + expf(-logit));
      const int idx = i * 1023 - (i * (i - 1)) / 2 + (j - i - 1);
      out[idx] = score;
      const bool mk = (score > 0.5f) && (stress[i] > smean) && (stress[j] > smean);
      out[P_PAIRS + idx] = mk ? 1.0f : 0.0f;
    }
  }
}

extern "C" void kernel_launch(void* const* d_in, const int* in_sizes, int n_in,
                              void* d_out, int out_size, void* d_ws, size_t ws_size,
                              hipStream_t stream) {
  const float* x     = (const float*)d_in[0];
  const float* ctx   = (const float*)d_in[1];
  const float* W1    = (const float*)d_in[2];
  const float* b1    = (const float*)d_in[3];
  const float* gamma = (const float*)d_in[4];
  const float* beta  = (const float*)d_in[5];
  const float* rmean = (const float*)d_in[6];
  const float* rvar  = (const float*)d_in[7];
  const float* W2    = (const float*)d_in[8];
  const float* b2    = (const float*)d_in[9];
  const float* W3    = (const float*)d_in[10];
  const float* b3    = (const float*)d_in[11];
  float* out = (float*)d_out;

  float* ws     = (float*)d_ws;
  float* pa     = ws;              // 1024*256 (cterm pre-folded)
  float* pb     = pa + 262144;     // 1024*256
  float* w2ft   = pb + 262144;     // 256*8 (transposed [m][e], BN-scaled)
  float* b2f    = w2ft + 2048;     // 8
  float* stress = b2f + 8;         // 1024

  hipLaunchKernelGGL(kA, dim3(257), dim3(256), 0, stream, x, ctx, W1, b1, gamma, beta,
                     rmean, rvar, W2, b2, pa, pb, stress, w2ft, b2f);
  hipLaunchKernelGGL(kC, dim3(NBLK), dim3(256), 0, stream, pa, pb, w2ft, b2f,
                     W3, b3, stress, out);
}

// Round 6
// 120.839 us; speedup vs baseline: 1.0872x; 1.0057x over previous
//
#include <hip/hip_runtime.h>
#include <math.h>

#define N_NODES 1024
#define F_DIM   128
#define M_DIM   256
#define E_DIM   8
#define P_PAIRS 523776   // N*(N-1)/2
#define NBLK    1056     // sum_{tj=0..31} (2*tj+2) 16x32 tiles
#define APITCH  33       // padded row pitch in float4 (bank-decorrelating)

typedef float v2f __attribute__((ext_vector_type(2)));

// ---------- Kernel A: pa/pb projections (+cterm folded) + stress; block 256 = BN fold ----------
// R21/R0 proven form, untouched (R19/R20 "fixes" both regressed ~+10us: the
// per-thread-row W1 stream is fully consumed, L2-resident, barrier-free).
__global__ __launch_bounds__(256) void kA(const float* __restrict__ x,
                                          const float* __restrict__ ctx,
                                          const float* __restrict__ W1,
                                          const float* __restrict__ b1,
                                          const float* __restrict__ gamma,
                                          const float* __restrict__ beta,
                                          const float* __restrict__ rmean,
                                          const float* __restrict__ rvar,
                                          const float* __restrict__ W2,
                                          const float* __restrict__ b2,
                                          float* __restrict__ pa,
                                          float* __restrict__ pb,
                                          float* __restrict__ stress,
                                          float* __restrict__ w2ft,
                                          float* __restrict__ b2f) {
  const int t = threadIdx.x;

  if (blockIdx.x == 256) {
    __shared__ float bnbs[256];
    const float s   = gamma[t] / sqrtf(rvar[t] + 1e-5f);
    bnbs[t] = beta[t] - s * rmean[t];
    #pragma unroll
    for (int e = 0; e < 8; ++e) w2ft[t * 8 + e] = W2[e * 256 + t] * s;
    __syncthreads();
    const int wv = t >> 6, lane = t & 63;
    #pragma unroll
    for (int r = 0; r < 2; ++r) {
      const int e = wv * 2 + r;
      float acc = 0.f;
      #pragma unroll
      for (int k = 0; k < 4; ++k) acc += W2[e * 256 + lane + 64 * k] * bnbs[lane + 64 * k];
      #pragma unroll
      for (int m = 32; m > 0; m >>= 1) acc += __shfl_xor(acc, m, 64);
      if (lane == 0) b2f[e] = acc + b2[e];
    }
    return;
  }

  __shared__ float xv[4][128];
  const int n0 = blockIdx.x * 4;
  if (t < 128) {
    ((float4*)&xv[0][0])[t] = ((const float4*)(x + (size_t)n0 * F_DIM))[t];
  }
  __syncthreads();

  {
    const int wv = t >> 6, lane = t & 63;
    const float a = xv[wv][lane], b = xv[wv][lane + 64];
    float sum = a + b;
    #pragma unroll
    for (int m = 32; m > 0; m >>= 1) sum += __shfl_xor(sum, m, 64);
    const float mean = sum * (1.0f / 128.0f);
    const float d0 = a - mean, d1 = b - mean;
    float ss = d0 * d0 + d1 * d1;
    #pragma unroll
    for (int m = 32; m > 0; m >>= 1) ss += __shfl_xor(ss, m, 64);
    if (lane == 0) stress[n0 + wv] = sqrtf(ss * (1.0f / 127.0f));
  }

  const float4* wrow = (const float4*)(W1 + (size_t)t * 260);  // W1 row-major [256][260]
  float accA[4] = {0.f, 0.f, 0.f, 0.f};
  float accB[4] = {0.f, 0.f, 0.f, 0.f};
  #pragma unroll 8
  for (int k4 = 0; k4 < 32; ++k4) {
    const float4 wa = wrow[k4];
    const float4 wb = wrow[32 + k4];
    #pragma unroll
    for (int nn = 0; nn < 4; ++nn) {
      const float4 xf = ((const float4*)&xv[nn][0])[k4];
      accA[nn] = fmaf(xf.w, wa.w, fmaf(xf.z, wa.z, fmaf(xf.y, wa.y, fmaf(xf.x, wa.x, accA[nn]))));
      accB[nn] = fmaf(xf.w, wb.w, fmaf(xf.z, wb.z, fmaf(xf.y, wb.y, fmaf(xf.x, wb.x, accB[nn]))));
    }
  }
  const float c0 = ctx[0], c1 = ctx[1], c2 = ctx[2], c3 = ctx[3];
  const float* rowt = W1 + (size_t)t * 260 + 256;
  const float ctv = b1[t] + c0 * rowt[0] + c1 * rowt[1] + c2 * rowt[2] + c3 * rowt[3];
  #pragma unroll
  for (int nn = 0; nn < 4; ++nn) {
    pa[(size_t)(n0 + nn) * M_DIM + t] = accA[nn] + ctv;   // cterm folded (bit-exact)
    pb[(size_t)(n0 + nn) * M_DIM + t] = accB[nn];
  }
}

// ---------- Kernel C: 1056 triangular 16x32 tiles, 256 threads, 2 pairs/thread ----------
// R22 (LDS-pipe theory, corrected): proper pipe floors are VALU ~7us, LDS
// ~16us (3 ds_read_b128/round at 12cy, 16.5 waves/CU) -> LDS is the max-
// demand pipe at 38% util. The A-operand is a 16-lane broadcast (4 distinct
// 16B addrs/wave) and pa rows are L1/L2-resident (8KB/block) -> serve A
// DIRECTLY FROM GLOBAL: moves 1 of 3 DS reads/round to the idle VMEM pipe
// (-33% LDS demand), deletes a4 + A staging (LDS 25.6->16.9KB), decouples
// the A wait from the lgkm-entangled weight s_load stream (vmcnt queue).
// Same floats, same op order -> bit-exact. If this is null, no pipe governs
// kC's wall and the structure is at its latency ceiling.
__global__ __launch_bounds__(256, 6) void kC(const float* __restrict__ pa,
                                             const float* __restrict__ pb,
                                             const float* __restrict__ w2ft,
                                             const float* __restrict__ b2f,
                                             const float* __restrict__ W3,
                                             const float* __restrict__ b3,
                                             const float* __restrict__ stress,
                                             float* __restrict__ out) {
  __shared__ float4 b4[32 * APITCH];   // 32 j-rows, 128-m chunk, pitch 33
  const int t = threadIdx.x;

  // decode p -> (tj, si): p = tj*(tj+1) + si, si in [0, 2*tj+2)
  const int p = blockIdx.x;
  int tj = (int)((sqrtf(4.0f * (float)p + 1.0f) - 1.0f) * 0.5f);
  while ((tj + 1) * (tj + 2) <= p) ++tj;
  while (tj * (tj + 1) > p) --tj;
  const int si = p - tj * (tj + 1);
  const int i0 = si * 16, j0 = tj * 32;

  const float4* pa4 = (const float4*)pa;
  const float4* pb4 = (const float4*)pb;
  const double* wdp = (const double*)w2ft;   // row m: 4 doubles = e-pairs

  // ---- chunk-0 B staging loads issued; stress-mean computed under their latency ----
  float4 rB[4];
  #pragma unroll
  for (int q = 0; q < 4; ++q) {
    const int d = q * 256 + t, r = d >> 5, c = d & 31;
    rB[q] = pb4[(size_t)(j0 + r) * 64 + c];
  }

  float ssum = 0.f;
  {
    const int lane = t & 63;
    #pragma unroll
    for (int k = 0; k < 16; ++k) ssum += stress[lane + 64 * k];
    #pragma unroll
    for (int m = 32; m > 0; m >>= 1) ssum += __shfl_xor(ssum, m, 64);
  }
  const float smean = ssum * (1.0f / 1024.0f);

  // ---- write chunk-0 B tile ----
  #pragma unroll
  for (int q = 0; q < 4; ++q) {
    const int d = q * 256 + t, r = d >> 5, c = d & 31;
    b4[r * APITCH + c] = rB[q];
  }
  __syncthreads();

  const int jx = t & 15;   // j pair: jx, jx+16
  const int iy = t >> 4;   // i within tile, 0..15
  v2f acc[8];              // per e: {acc for j=jx, acc for j=jx+16}
  #pragma unroll
  for (int e = 0; e < 8; ++e) acc[e] = (v2f){0.f, 0.f};

  const float4* aG    = pa4 + (size_t)(i0 + iy) * 64;   // per-thread global A row (L1-resident)
  const float4* bRow0 = b4 + jx * APITCH;
  const float4* bRow1 = b4 + (jx + 16) * APITCH;

  auto computeChunk = [&](int cw) {
    #pragma unroll 2
    for (int m4 = 0; m4 < 32; ++m4) {
      const float4 A  = aG[cw + m4];      // VMEM: 4 distinct 16B addrs/wave, L1 broadcast
      const float4 B0 = bRow0[m4];
      const float4 B1 = bRow1[m4];
      const double* wr = wdp + (size_t)(cw + m4) * 16;   // 4 m x 4 e-pair doubles
      const float* Af  = (const float*)&A;
      const float* B0f = (const float*)&B0;
      const float* B1f = (const float*)&B1;
      #pragma unroll
      for (int mm = 0; mm < 4; ++mm) {
        v2f R;
        R.x = fmaxf(Af[mm] + B0f[mm], 0.f);   // r for (i, jx)
        R.y = fmaxf(Af[mm] + B1f[mm], 0.f);   // r for (i, jx+16)
        #pragma unroll
        for (int k = 0; k < 4; ++k) {
          const double wp = wr[mm * 4 + k];   // {w[m][2k], w[m][2k+1]} in SGPR pair
          // even e = 2k: broadcast LO word of wp to both halves (R9-proven form)
          asm("v_pk_fma_f32 %0, %1, %2, %0 op_sel:[0,0,0] op_sel_hi:[0,1,1]"
              : "+v"(acc[2 * k]) : "s"(wp), "v"(R));
          // odd e = 2k+1: broadcast HI word of wp to both halves
          asm("v_pk_fma_f32 %0, %1, %2, %0 op_sel:[1,0,0] op_sel_hi:[1,1,1]"
              : "+v"(acc[2 * k + 1]) : "s"(wp), "v"(R));
        }
      }
    }
  };

  computeChunk(0);
  __syncthreads();

  // ---- stage chunk 1 B tile (transient regs) ----
  #pragma unroll
  for (int q = 0; q < 4; ++q) {
    const int d = q * 256 + t, r = d >> 5, c = d & 31;
    rB[q] = pb4[(size_t)(j0 + r) * 64 + 32 + c];
  }
  #pragma unroll
  for (int q = 0; q < 4; ++q) {
    const int d = q * 256 + t, r = d >> 5, c = d & 31;
    b4[r * APITCH + c] = rB[q];
  }
  __syncthreads();

  computeChunk(32);

  // ---- epilogue ----
  float w3v[8], b2v[8];
  #pragma unroll
  for (int e = 0; e < 8; ++e) { w3v[e] = W3[e]; b2v[e] = b2f[e]; }
  const float b3v = b3[0];
  const int i = i0 + iy;
  #pragma unroll
  for (int jb = 0; jb < 2; ++jb) {
    const int j = j0 + jx + jb * 16;
    if (i < j) {
      float logit = b3v;
      #pragma unroll
      for (int e = 0; e < 8; ++e) {
        const float av = jb ? acc[e].y : acc[e].x;
        const float h2 = fmaxf(av + b2v[e], 0.f);
        logit = fmaf(w3v[e], h2, logit);
      }
      const float score = 1.0f / (1.0f + expf(-logit));
      const int idx = i * 1023 - (i * (i - 1)) / 2 + (j - i - 1);
      out[idx] = score;
      const bool mk = (score > 0.5f) && (stress[i] > smean) && (stress[j] > smean);
      out[P_PAIRS + idx] = mk ? 1.0f : 0.0f;
    }
  }
}

extern "C" void kernel_launch(void* const* d_in, const int* in_sizes, int n_in,
                              void* d_out, int out_size, void* d_ws, size_t ws_size,
                              hipStream_t stream) {
  const float* x     = (const float*)d_in[0];
  const float* ctx   = (const float*)d_in[1];
  const float* W1    = (const float*)d_in[2];
  const float* b1    = (const float*)d_in[3];
  const float* gamma = (const float*)d_in[4];
  const float* beta  = (const float*)d_in[5];
  const float* rmean = (const float*)d_in[6];
  const float* rvar  = (const float*)d_in[7];
  const float* W2    = (const float*)d_in[8];
  const float* b2    = (const float*)d_in[9];
  const float* W3    = (const float*)d_in[10];
  const float* b3    = (const float*)d_in[11];
  float* out = (float*)d_out;

  float* ws     = (float*)d_ws;
  float* pa     = ws;              // 1024*256 (cterm pre-folded)
  float* pb     = pa + 262144;     // 1024*256
  float* w2ft   = pb + 262144;     // 256*8 (transposed [m][e], BN-scaled)
  float* b2f    = w2ft + 2048;     // 8
  float* stress = b2f + 8;         // 1024

  hipLaunchKernelGGL(kA, dim3(257), dim3(256), 0, stream, x, ctx, W1, b1, gamma, beta,
                     rmean, rvar, W2, b2, pa, pb, stress, w2ft, b2f);
  hipLaunchKernelGGL(kC, dim3(NBLK), dim3(256), 0, stream, pa, pb, w2ft, b2f,
                     W3, b3, stress, out);
}

// Round 7
// 119.969 us; speedup vs baseline: 1.0951x; 1.0073x over previous
//
#include <hip/hip_runtime.h>
#include <math.h>

#define N_NODES 1024
#define F_DIM   128
#define M_DIM   256
#define E_DIM   8
#define P_PAIRS 523776   // N*(N-1)/2
#define NBLK    1056     // sum_{tj=0..31} (2*tj+2) 16x32 tiles
#define APITCH  33       // padded row pitch in float4 (bank-decorrelating)

typedef float v2f __attribute__((ext_vector_type(2)));

// ---------- Kernel A: pa/pb projections (+cterm folded) + stress; block 256 = BN fold ----------
// Proven form (best totals 119.4/120.1/121.5). R19/R20 coalescing rewrites both
// regressed ~+10us: the per-thread-row W1 stream is fully consumed, L2-resident,
// and barrier-free; LDS-staged variants paid 16 barriers/block at 1 block/CU.
__global__ __launch_bounds__(256) void kA(const float* __restrict__ x,
                                          const float* __restrict__ ctx,
                                          const float* __restrict__ W1,
                                          const float* __restrict__ b1,
                                          const float* __restrict__ gamma,
                                          const float* __restrict__ beta,
                                          const float* __restrict__ rmean,
                                          const float* __restrict__ rvar,
                                          const float* __restrict__ W2,
                                          const float* __restrict__ b2,
                                          float* __restrict__ pa,
                                          float* __restrict__ pb,
                                          float* __restrict__ stress,
                                          float* __restrict__ w2ft,
                                          float* __restrict__ b2f) {
  const int t = threadIdx.x;

  if (blockIdx.x == 256) {
    __shared__ float bnbs[256];
    const float s   = gamma[t] / sqrtf(rvar[t] + 1e-5f);
    bnbs[t] = beta[t] - s * rmean[t];
    #pragma unroll
    for (int e = 0; e < 8; ++e) w2ft[t * 8 + e] = W2[e * 256 + t] * s;
    __syncthreads();
    const int wv = t >> 6, lane = t & 63;
    #pragma unroll
    for (int r = 0; r < 2; ++r) {
      const int e = wv * 2 + r;
      float acc = 0.f;
      #pragma unroll
      for (int k = 0; k < 4; ++k) acc += W2[e * 256 + lane + 64 * k] * bnbs[lane + 64 * k];
      #pragma unroll
      for (int m = 32; m > 0; m >>= 1) acc += __shfl_xor(acc, m, 64);
      if (lane == 0) b2f[e] = acc + b2[e];
    }
    return;
  }

  __shared__ float xv[4][128];
  const int n0 = blockIdx.x * 4;
  if (t < 128) {
    ((float4*)&xv[0][0])[t] = ((const float4*)(x + (size_t)n0 * F_DIM))[t];
  }
  __syncthreads();

  {
    const int wv = t >> 6, lane = t & 63;
    const float a = xv[wv][lane], b = xv[wv][lane + 64];
    float sum = a + b;
    #pragma unroll
    for (int m = 32; m > 0; m >>= 1) sum += __shfl_xor(sum, m, 64);
    const float mean = sum * (1.0f / 128.0f);
    const float d0 = a - mean, d1 = b - mean;
    float ss = d0 * d0 + d1 * d1;
    #pragma unroll
    for (int m = 32; m > 0; m >>= 1) ss += __shfl_xor(ss, m, 64);
    if (lane == 0) stress[n0 + wv] = sqrtf(ss * (1.0f / 127.0f));
  }

  const float4* wrow = (const float4*)(W1 + (size_t)t * 260);  // W1 row-major [256][260]
  float accA[4] = {0.f, 0.f, 0.f, 0.f};
  float accB[4] = {0.f, 0.f, 0.f, 0.f};
  #pragma unroll 8
  for (int k4 = 0; k4 < 32; ++k4) {
    const float4 wa = wrow[k4];
    const float4 wb = wrow[32 + k4];
    #pragma unroll
    for (int nn = 0; nn < 4; ++nn) {
      const float4 xf = ((const float4*)&xv[nn][0])[k4];
      accA[nn] = fmaf(xf.w, wa.w, fmaf(xf.z, wa.z, fmaf(xf.y, wa.y, fmaf(xf.x, wa.x, accA[nn]))));
      accB[nn] = fmaf(xf.w, wb.w, fmaf(xf.z, wb.z, fmaf(xf.y, wb.y, fmaf(xf.x, wb.x, accB[nn]))));
    }
  }
  const float c0 = ctx[0], c1 = ctx[1], c2 = ctx[2], c3 = ctx[3];
  const float* rowt = W1 + (size_t)t * 260 + 256;
  const float ctv = b1[t] + c0 * rowt[0] + c1 * rowt[1] + c2 * rowt[2] + c3 * rowt[3];
  #pragma unroll
  for (int nn = 0; nn < 4; ++nn) {
    pa[(size_t)(n0 + nn) * M_DIM + t] = accA[nn] + ctv;   // cterm folded (bit-exact)
    pb[(size_t)(n0 + nn) * M_DIM + t] = accB[nn];
  }
}

// ---------- Kernel C: 1056 triangular 16x32 tiles, 256 threads, 2 pairs/thread ----------
// R16 form -- the measured optimum (41.7-41.9 us, four sessions). Attack
// ledger: R17 sw-pipeline null (compiler already schedules); R18 2ix2j
// micro-tile -4us (residency loss); R22 A-from-global -1.4us (LDS demand
// -33% onto idle VMEM pipe, still slower). All pipes individually <55%
// (VALU 52%, LDS-demand 38%, HBM 3%, conflicts 0) and the wall is invariant
// to single-pipe demand cuts -> dependent-issue/latency-structure bound at
// ~4 waves/SIMD. This is the structure's floor at HIP source level.
__global__ __launch_bounds__(256, 6) void kC(const float* __restrict__ pa,
                                             const float* __restrict__ pb,
                                             const float* __restrict__ w2ft,
                                             const float* __restrict__ b2f,
                                             const float* __restrict__ W3,
                                             const float* __restrict__ b3,
                                             const float* __restrict__ stress,
                                             float* __restrict__ out) {
  __shared__ float4 a4[16 * APITCH];   // 16 i-rows, 128-m chunk, pitch 33
  __shared__ float4 b4[32 * APITCH];   // 32 j-rows
  const int t = threadIdx.x;

  // decode p -> (tj, si): p = tj*(tj+1) + si, si in [0, 2*tj+2)
  const int p = blockIdx.x;
  int tj = (int)((sqrtf(4.0f * (float)p + 1.0f) - 1.0f) * 0.5f);
  while ((tj + 1) * (tj + 2) <= p) ++tj;
  while (tj * (tj + 1) > p) --tj;
  const int si = p - tj * (tj + 1);
  const int i0 = si * 16, j0 = tj * 32;

  const float4* pa4 = (const float4*)pa;
  const float4* pb4 = (const float4*)pb;
  const double* wdp = (const double*)w2ft;   // row m: 4 doubles = e-pairs

  // ---- chunk-0 staging loads issued; stress-mean computed under their latency ----
  float4 rA[2], rB[4];
  #pragma unroll
  for (int q = 0; q < 2; ++q) {
    const int d = q * 256 + t, r = d >> 5, c = d & 31;
    rA[q] = pa4[(size_t)(i0 + r) * 64 + c];
  }
  #pragma unroll
  for (int q = 0; q < 4; ++q) {
    const int d = q * 256 + t, r = d >> 5, c = d & 31;
    rB[q] = pb4[(size_t)(j0 + r) * 64 + c];
  }

  float ssum = 0.f;
  {
    const int lane = t & 63;
    #pragma unroll
    for (int k = 0; k < 16; ++k) ssum += stress[lane + 64 * k];
    #pragma unroll
    for (int m = 32; m > 0; m >>= 1) ssum += __shfl_xor(ssum, m, 64);
  }
  const float smean = ssum * (1.0f / 1024.0f);

  // ---- write chunk-0 tiles (transient regs die here; no spill risk) ----
  #pragma unroll
  for (int q = 0; q < 2; ++q) {
    const int d = q * 256 + t, r = d >> 5, c = d & 31;
    a4[r * APITCH + c] = rA[q];
  }
  #pragma unroll
  for (int q = 0; q < 4; ++q) {
    const int d = q * 256 + t, r = d >> 5, c = d & 31;
    b4[r * APITCH + c] = rB[q];
  }
  __syncthreads();

  const int jx = t & 15;   // j pair: jx, jx+16
  const int iy = t >> 4;   // i within tile, 0..15
  v2f acc[8];              // per e: {acc for j=jx, acc for j=jx+16}
  #pragma unroll
  for (int e = 0; e < 8; ++e) acc[e] = (v2f){0.f, 0.f};

  const float4* aRow  = a4 + iy * APITCH;          // bases hoisted; m4 offsets immediate
  const float4* bRow0 = b4 + jx * APITCH;
  const float4* bRow1 = b4 + (jx + 16) * APITCH;

  auto computeChunk = [&](int cw) {
    #pragma unroll 2
    for (int m4 = 0; m4 < 32; ++m4) {
      const float4 A  = aRow[m4];
      const float4 B0 = bRow0[m4];
      const float4 B1 = bRow1[m4];
      const double* wr = wdp + (size_t)(cw + m4) * 16;   // 4 m x 4 e-pair doubles
      const float* Af  = (const float*)&A;
      const float* B0f = (const float*)&B0;
      const float* B1f = (const float*)&B1;
      #pragma unroll
      for (int mm = 0; mm < 4; ++mm) {
        v2f R;
        R.x = fmaxf(Af[mm] + B0f[mm], 0.f);   // r for (i, jx)
        R.y = fmaxf(Af[mm] + B1f[mm], 0.f);   // r for (i, jx+16)
        #pragma unroll
        for (int k = 0; k < 4; ++k) {
          const double wp = wr[mm * 4 + k];   // {w[m][2k], w[m][2k+1]} in SGPR pair
          // even e = 2k: broadcast LO word of wp to both halves (R9-proven form)
          asm("v_pk_fma_f32 %0, %1, %2, %0 op_sel:[0,0,0] op_sel_hi:[0,1,1]"
              : "+v"(acc[2 * k]) : "s"(wp), "v"(R));
          // odd e = 2k+1: broadcast HI word of wp to both halves
          asm("v_pk_fma_f32 %0, %1, %2, %0 op_sel:[1,0,0] op_sel_hi:[1,1,1]"
              : "+v"(acc[2 * k + 1]) : "s"(wp), "v"(R));
        }
      }
    }
  };

  computeChunk(0);
  __syncthreads();

  // ---- stage chunk 1 (transient regs again) ----
  #pragma unroll
  for (int q = 0; q < 2; ++q) {
    const int d = q * 256 + t, r = d >> 5, c = d & 31;
    rA[q] = pa4[(size_t)(i0 + r) * 64 + 32 + c];
  }
  #pragma unroll
  for (int q = 0; q < 4; ++q) {
    const int d = q * 256 + t, r = d >> 5, c = d & 31;
    rB[q] = pb4[(size_t)(j0 + r) * 64 + 32 + c];
  }
  #pragma unroll
  for (int q = 0; q < 2; ++q) {
    const int d = q * 256 + t, r = d >> 5, c = d & 31;
    a4[r * APITCH + c] = rA[q];
  }
  #pragma unroll
  for (int q = 0; q < 4; ++q) {
    const int d = q * 256 + t, r = d >> 5, c = d & 31;
    b4[r * APITCH + c] = rB[q];
  }
  __syncthreads();

  computeChunk(32);

  // ---- epilogue ----
  float w3v[8], b2v[8];
  #pragma unroll
  for (int e = 0; e < 8; ++e) { w3v[e] = W3[e]; b2v[e] = b2f[e]; }
  const float b3v = b3[0];
  const int i = i0 + iy;
  #pragma unroll
  for (int jb = 0; jb < 2; ++jb) {
    const int j = j0 + jx + jb * 16;
    if (i < j) {
      float logit = b3v;
      #pragma unroll
      for (int e = 0; e < 8; ++e) {
        const float av = jb ? acc[e].y : acc[e].x;
        const float h2 = fmaxf(av + b2v[e], 0.f);
        logit = fmaf(w3v[e], h2, logit);
      }
      const float score = 1.0f / (1.0f + expf(-logit));
      const int idx = i * 1023 - (i * (i - 1)) / 2 + (j - i - 1);
      out[idx] = score;
      const bool mk = (score > 0.5f) && (stress[i] > smean) && (stress[j] > smean);
      out[P_PAIRS + idx] = mk ? 1.0f : 0.0f;
    }
  }
}

extern "C" void kernel_launch(void* const* d_in, const int* in_sizes, int n_in,
                              void* d_out, int out_size, void* d_ws, size_t ws_size,
                              hipStream_t stream) {
  const float* x     = (const float*)d_in[0];
  const float* ctx   = (const float*)d_in[1];
  const float* W1    = (const float*)d_in[2];
  const float* b1    = (const float*)d_in[3];
  const float* gamma = (const float*)d_in[4];
  const float* beta  = (const float*)d_in[5];
  const float* rmean = (const float*)d_in[6];
  const float* rvar  = (const float*)d_in[7];
  const float* W2    = (const float*)d_in[8];
  const float* b2    = (const float*)d_in[9];
  const float* W3    = (const float*)d_in[10];
  const float* b3    = (const float*)d_in[11];
  float* out = (float*)d_out;

  float* ws     = (float*)d_ws;
  float* pa     = ws;              // 1024*256 (cterm pre-folded)
  float* pb     = pa + 262144;     // 1024*256
  float* w2ft   = pb + 262144;     // 256*8 (transposed [m][e], BN-scaled)
  float* b2f    = w2ft + 2048;     // 8
  float* stress = b2f + 8;         // 1024

  hipLaunchKernelGGL(kA, dim3(257), dim3(256), 0, stream, x, ctx, W1, b1, gamma, beta,
                     rmean, rvar, W2, b2, pa, pb, stress, w2ft, b2f);
  hipLaunchKernelGGL(kC, dim3(NBLK), dim3(256), 0, stream, pa, pb, w2ft, b2f,
                     W3, b3, stress, out);
}